// Round 1
// baseline (63.741 us; speedup 1.0000x reference)
//
#include <hip/hip_runtime.h>
#include <math.h>

// Shapes (fixed by the reference): B=16, C=256, deeper 32x32, shallower 64x64.
// ws layout: gp[16*512] | h[16*256] | sig[16*256]  (floats, 64 KB total)

__global__ __launch_bounds__(256) void pool_kernel(const float* __restrict__ deeper,
                                                   const float* __restrict__ shallower,
                                                   float* __restrict__ gp) {
    const int idx = blockIdx.x;   // [0,4096): shallower slices; [4096,8192): deeper slices
    const int t = threadIdx.x;
    float sum;
    if (idx < 4096) {
        const float4* src = (const float4*)(shallower + (size_t)idx * 4096);
        float4 a = src[t];
        float4 b = src[t + 256];
        float4 c = src[t + 512];
        float4 d = src[t + 768];
        sum = (a.x + a.y + a.z + a.w) + (b.x + b.y + b.z + b.w)
            + (c.x + c.y + c.z + c.w) + (d.x + d.y + d.z + d.w);
    } else {
        const float4* src = (const float4*)(deeper + (size_t)(idx - 4096) * 1024);
        float4 a = src[t];
        sum = a.x + a.y + a.z + a.w;
    }
    // wave64 butterfly reduce
    #pragma unroll
    for (int off = 32; off > 0; off >>= 1) sum += __shfl_down(sum, off, 64);
    __shared__ float red[4];
    if ((t & 63) == 0) red[t >> 6] = sum;
    __syncthreads();
    if (t == 0) {
        float tot = red[0] + red[1] + red[2] + red[3];
        if (idx < 4096) {
            int b = idx >> 8, c = idx & 255;
            gp[b * 512 + c] = tot * (1.0f / 4096.0f);            // shallow_pool first
        } else {
            int j = idx - 4096;
            int b = j >> 8, c = j & 255;
            gp[b * 512 + 256 + c] = tot * (1.0f / 1024.0f);      // deeper_pool second
        }
    }
}

__global__ __launch_bounds__(256) void mlp1_kernel(const float* __restrict__ gp,
                                                   const float* __restrict__ w1,
                                                   const float* __restrict__ b1,
                                                   float* __restrict__ h) {
    const int b = blockIdx.x;    // 16
    const int o = threadIdx.x;   // 256
    const float4* gv = (const float4*)(gp + b * 512);
    const float4* wv = (const float4*)(w1 + (size_t)o * 512);
    float acc = b1[o];
    #pragma unroll 8
    for (int i = 0; i < 128; ++i) {
        float4 g = gv[i], w = wv[i];
        acc += g.x * w.x + g.y * w.y + g.z * w.z + g.w * w.w;
    }
    h[b * 256 + o] = fmaxf(acc, 0.0f);
}

__global__ __launch_bounds__(256) void mlp2_kernel(const float* __restrict__ h,
                                                   const float* __restrict__ w2,
                                                   const float* __restrict__ b2,
                                                   float* __restrict__ sig) {
    const int b = blockIdx.x;    // 16
    const int o = threadIdx.x;   // 256
    const float4* hv = (const float4*)(h + b * 256);
    const float4* wv = (const float4*)(w2 + (size_t)o * 256);
    float acc = b2[o];
    #pragma unroll 8
    for (int i = 0; i < 64; ++i) {
        float4 g = hv[i], w = wv[i];
        acc += g.x * w.x + g.y * w.y + g.z * w.z + g.w * w.w;
    }
    sig[b * 256 + o] = 1.0f / (1.0f + expf(-acc));
}

__global__ __launch_bounds__(256) void out_kernel(const float* __restrict__ deeper,
                                                  const float* __restrict__ shallower,
                                                  const float* __restrict__ sig,
                                                  float* __restrict__ out) {
    const int bc = blockIdx.x;   // 4096 = (b*256 + c)
    const int t = threadIdx.x;
    __shared__ float tile[1024]; // 32x32 deeper slice
    const float4* dsrc = (const float4*)(deeper + (size_t)bc * 1024);
    ((float4*)tile)[t] = dsrc[t];
    const float s = sig[bc];
    __syncthreads();
    const float4* ssrc = (const float4*)(shallower + (size_t)bc * 4096);
    float4* dst = (float4*)(out + (size_t)bc * 4096);
    #pragma unroll
    for (int j = 0; j < 4; ++j) {
        const int f4 = t + j * 256;      // float4 index in [0,1024)
        const int y = f4 >> 4;           // 16 float4 per 64-wide row
        const int x0 = (f4 & 15) * 4;
        float4 sh = ssrc[f4];
        // bilinear, half-pixel centers, clamp-to-edge (== jax edge renormalization)
        const int yy = 2 * y - 1;
        const int yl = yy >> 2;          // floor((2y-1)/4), arithmetic shift handles -1
        const float wy = (float)(yy & 3) * 0.25f;
        const int y0c = yl < 0 ? 0 : yl;
        const int y1c = (yl + 1) > 31 ? 31 : (yl + 1);
        const float* r0 = tile + y0c * 32;
        const float* r1 = tile + y1c * 32;
        float up[4];
        #pragma unroll
        for (int k = 0; k < 4; ++k) {
            const int x = x0 + k;
            const int xx = 2 * x - 1;
            const int xl = xx >> 2;
            const float wx = (float)(xx & 3) * 0.25f;
            const int x0c = xl < 0 ? 0 : xl;
            const int x1c = (xl + 1) > 31 ? 31 : (xl + 1);
            const float top = r0[x0c] * (1.0f - wx) + r0[x1c] * wx;
            const float bot = r1[x0c] * (1.0f - wx) + r1[x1c] * wx;
            up[k] = top * (1.0f - wy) + bot * wy;
        }
        float4 o;
        o.x = sh.x * s + up[0];
        o.y = sh.y * s + up[1];
        o.z = sh.z * s + up[2];
        o.w = sh.w * s + up[3];
        dst[f4] = o;
    }
}

extern "C" void kernel_launch(void* const* d_in, const int* in_sizes, int n_in,
                              void* d_out, int out_size, void* d_ws, size_t ws_size,
                              hipStream_t stream) {
    const float* deeper    = (const float*)d_in[0];  // [16,256,32,32]
    const float* shallower = (const float*)d_in[1];  // [16,256,64,64]
    const float* w1        = (const float*)d_in[2];  // [256,512]
    const float* b1        = (const float*)d_in[3];  // [256]
    const float* w2        = (const float*)d_in[4];  // [256,256]
    const float* b2        = (const float*)d_in[5];  // [256]
    float* out = (float*)d_out;

    float* gp  = (float*)d_ws;        // 16*512
    float* h   = gp + 16 * 512;       // 16*256
    float* sg  = h + 16 * 256;        // 16*256

    hipLaunchKernelGGL(pool_kernel, dim3(8192), dim3(256), 0, stream, deeper, shallower, gp);
    hipLaunchKernelGGL(mlp1_kernel, dim3(16), dim3(256), 0, stream, gp, w1, b1, h);
    hipLaunchKernelGGL(mlp2_kernel, dim3(16), dim3(256), 0, stream, h, w2, b2, sg);
    hipLaunchKernelGGL(out_kernel, dim3(4096), dim3(256), 0, stream, deeper, shallower, sg, out);
}

// Round 2
// 57.800 us; speedup vs baseline: 1.1028x; 1.1028x over previous
//
#include <hip/hip_runtime.h>
#include <math.h>

// Shapes fixed by the reference: B=16, C=256, deeper 32x32, shallower 64x64.
// ws layout (floats): gp[16*512] | h[16*256] | sig[16*256]

// One block per (b,c): mean over shallower 64x64 slice AND deeper 32x32 slice.
__global__ __launch_bounds__(256) void pool_kernel(const float* __restrict__ deeper,
                                                   const float* __restrict__ shallower,
                                                   float* __restrict__ gp) {
    const int bc = blockIdx.x;   // 0..4095 = b*256 + c
    const int t = threadIdx.x;
    const float4* ssrc = (const float4*)(shallower + (size_t)bc * 4096);
    const float4* dsrc = (const float4*)(deeper + (size_t)bc * 1024);
    float4 a = ssrc[t];
    float4 b = ssrc[t + 256];
    float4 c = ssrc[t + 512];
    float4 d = ssrc[t + 768];
    float4 e = dsrc[t];
    float s_sh = (a.x + a.y + a.z + a.w) + (b.x + b.y + b.z + b.w)
               + (c.x + c.y + c.z + c.w) + (d.x + d.y + d.z + d.w);
    float s_dp = e.x + e.y + e.z + e.w;
    #pragma unroll
    for (int off = 32; off > 0; off >>= 1) {
        s_sh += __shfl_down(s_sh, off, 64);
        s_dp += __shfl_down(s_dp, off, 64);
    }
    __shared__ float red_sh[4], red_dp[4];
    if ((t & 63) == 0) { red_sh[t >> 6] = s_sh; red_dp[t >> 6] = s_dp; }
    __syncthreads();
    if (t == 0) {
        float tot_sh = red_sh[0] + red_sh[1] + red_sh[2] + red_sh[3];
        float tot_dp = red_dp[0] + red_dp[1] + red_dp[2] + red_dp[3];
        int bb = bc >> 8, cc = bc & 255;
        gp[bb * 512 + cc]       = tot_sh * (1.0f / 4096.0f);  // shallow_pool (first half)
        gp[bb * 512 + 256 + cc] = tot_dp * (1.0f / 1024.0f);  // deeper_pool (second half)
    }
}

// mlp1: h[b,o] = relu(gp[b,:512] . w1[o,:512] + b1[o])
// 32 blocks x 256 thr: block j covers o in [8j, 8j+8), all 16 b, split-K=2.
__global__ __launch_bounds__(256) void mlp1_kernel(const float* __restrict__ gp,
                                                   const float* __restrict__ w1,
                                                   const float* __restrict__ b1,
                                                   float* __restrict__ h) {
    const int j = blockIdx.x;
    const int t = threadIdx.x;
    const int half = t >> 7;          // 0/1
    const int b = (t >> 3) & 15;
    const int oo = t & 7;
    const int o = j * 8 + oo;
    const float4* gv = (const float4*)(gp + b * 512 + half * 256);
    const float4* wv = (const float4*)(w1 + (size_t)o * 512 + half * 256);
    float acc = 0.0f;
    #pragma unroll 8
    for (int i = 0; i < 64; ++i) {
        float4 g = gv[i], w = wv[i];
        acc += g.x * w.x + g.y * w.y + g.z * w.z + g.w * w.w;
    }
    __shared__ float part[256];
    part[t] = acc;
    __syncthreads();
    if (t < 128) {
        float v = part[t] + part[t + 128] + b1[o];
        h[b * 256 + o] = fmaxf(v, 0.0f);
    }
}

// mlp2: sig[b,o] = sigmoid(h[b,:256] . w2[o,:256] + b2[o]) ; same decomposition.
__global__ __launch_bounds__(256) void mlp2_kernel(const float* __restrict__ h,
                                                   const float* __restrict__ w2,
                                                   const float* __restrict__ b2,
                                                   float* __restrict__ sig) {
    const int j = blockIdx.x;
    const int t = threadIdx.x;
    const int half = t >> 7;
    const int b = (t >> 3) & 15;
    const int oo = t & 7;
    const int o = j * 8 + oo;
    const float4* hv = (const float4*)(h + b * 256 + half * 128);
    const float4* wv = (const float4*)(w2 + (size_t)o * 256 + half * 128);
    float acc = 0.0f;
    #pragma unroll 8
    for (int i = 0; i < 32; ++i) {
        float4 g = hv[i], w = wv[i];
        acc += g.x * w.x + g.y * w.y + g.z * w.z + g.w * w.w;
    }
    __shared__ float part[256];
    part[t] = acc;
    __syncthreads();
    if (t < 128) {
        float v = part[t] + part[t + 128] + b2[o];
        sig[b * 256 + o] = 1.0f / (1.0f + expf(-v));
    }
}

// out = shallower * sigmoid(gate) + bilinear_upsample2x(deeper)
// One block per (b,c). LDS tile stride 36 (float4-aligned, bank-spread).
__global__ __launch_bounds__(256) void out_kernel(const float* __restrict__ deeper,
                                                  const float* __restrict__ shallower,
                                                  const float* __restrict__ sig,
                                                  float* __restrict__ out) {
    const int bc = blockIdx.x;   // 4096
    const int t = threadIdx.x;
    __shared__ float tile[32 * 36];
    const float4* dsrc = (const float4*)(deeper + (size_t)bc * 1024);
    {
        float4 v = dsrc[t];              // t = row*8 + col4
        int row = t >> 3, col4 = t & 7;
        *(float4*)(tile + row * 36 + col4 * 4) = v;   // byte addr = row*144 + col4*16: 16B aligned
    }
    const float s = sig[bc];
    __syncthreads();
    const float4* ssrc = (const float4*)(shallower + (size_t)bc * 4096);
    float4* dst = (float4*)(out + (size_t)bc * 4096);
    #pragma unroll
    for (int j = 0; j < 4; ++j) {
        const int f4 = t + j * 256;      // 0..1023
        const int y = f4 >> 4;           // 0..63
        const int m = f4 & 15;           // output x = 4m..4m+3
        const int yy = 2 * y - 1;
        const int yl = yy >> 2;
        const float wy = (float)(yy & 3) * 0.25f;
        const float wy1 = 1.0f - wy;
        const int y0 = yl < 0 ? 0 : yl;
        const int y1 = (yl + 1) > 31 ? 31 : (yl + 1);
        const float* r0 = tile + y0 * 36;
        const float* r1 = tile + y1 * 36;
        const int xa = (2 * m - 1) < 0 ? 0 : (2 * m - 1);
        const int xd = (2 * m + 2) > 31 ? 31 : (2 * m + 2);
        // vertical interpolation of the 4 needed input columns
        const float A = r0[xa]        * wy1 + r1[xa]        * wy;
        const float Bv = r0[2 * m]     * wy1 + r1[2 * m]     * wy;
        const float Cv = r0[2 * m + 1] * wy1 + r1[2 * m + 1] * wy;
        const float D = r0[xd]        * wy1 + r1[xd]        * wy;
        float4 sh = ssrc[f4];
        float4 o;
        o.x = fmaf(sh.x, s, 0.25f * A  + 0.75f * Bv);
        o.y = fmaf(sh.y, s, 0.75f * Bv + 0.25f * Cv);
        o.z = fmaf(sh.z, s, 0.25f * Bv + 0.75f * Cv);
        o.w = fmaf(sh.w, s, 0.75f * Cv + 0.25f * D);
        dst[f4] = o;
    }
}

extern "C" void kernel_launch(void* const* d_in, const int* in_sizes, int n_in,
                              void* d_out, int out_size, void* d_ws, size_t ws_size,
                              hipStream_t stream) {
    const float* deeper    = (const float*)d_in[0];  // [16,256,32,32]
    const float* shallower = (const float*)d_in[1];  // [16,256,64,64]
    const float* w1        = (const float*)d_in[2];  // [256,512]
    const float* b1        = (const float*)d_in[3];  // [256]
    const float* w2        = (const float*)d_in[4];  // [256,256]
    const float* b2        = (const float*)d_in[5];  // [256]
    float* out = (float*)d_out;

    float* gp  = (float*)d_ws;        // 16*512
    float* h   = gp + 16 * 512;       // 16*256
    float* sg  = h + 16 * 256;        // 16*256

    hipLaunchKernelGGL(pool_kernel, dim3(4096), dim3(256), 0, stream, deeper, shallower, gp);
    hipLaunchKernelGGL(mlp1_kernel, dim3(32), dim3(256), 0, stream, gp, w1, b1, h);
    hipLaunchKernelGGL(mlp2_kernel, dim3(32), dim3(256), 0, stream, h, w2, b2, sg);
    hipLaunchKernelGGL(out_kernel, dim3(4096), dim3(256), 0, stream, deeper, shallower, sg, out);
}